// Round 12
// baseline (89.250 us; speedup 1.0000x reference)
//
#include <hip/hip_runtime.h>
#include <math.h>

#define SEQ   2048
#define NH    8
#define DH    64          // p
#define DS    16          // n
#define NBH   512         // BATCH * NH
#define OUTBH 1024        // DH * DS
#define CT    16          // timesteps per chunk (per-wave staging unit)
#define XCH   1024        // CT*DH floats of X per chunk
#define CHF   1280        // chunk floats: X (1024) + B (256) = 5 KB
#define RS    18          // epilogue reduce row stride (floats) — conflict-free
#define WSTR  (64 * RS)   // per-wave reduce tile (1152 floats)

typedef float f4 __attribute__((ext_vector_type(4)));
#define AS1 __attribute__((address_space(1)))
#define AS3 __attribute__((address_space(3)))

// Stage one 16-t chunk (X: 4 KB as 4 ops, B: 1 KB as 1 op) into this wave's
// private LDS buffer. Exactly 5 global_load_lds per call (static vmcnt math).
// LDS dest is the wave-uniform base; HW appends lane*16B (linear layout).
__device__ __forceinline__ void stage16(const float* __restrict__ Xrow,
                                        const float* __restrict__ Brow,
                                        float* buf, int ct0, int lane)
{
#pragma unroll
    for (int r = 0; r < 4; ++r) {
        const float* g = Xrow + (size_t)(ct0 + r * 4 + (lane >> 4)) * (NH * DH)
                              + (lane & 15) * 4;
        __builtin_amdgcn_global_load_lds((const AS1 void*)g,
                                         (AS3 void*)(buf + r * 256), 16, 0, 0);
    }
    const float* g = Brow + (size_t)(ct0 + (lane >> 2)) * (NH * DS)
                          + (lane & 3) * 4;
    __builtin_amdgcn_global_load_lds((const AS1 void*)g,
                                     (AS3 void*)(buf + XCH), 16, 0, 0);
}

// One block per (segment, b, h); 4 waves. Wave w owns t in
// [t0 + w*WT, t0 + (w+1)*WT), WT = seglen/4, as NCH = WT/16 private chunks,
// double-buffered, counted vmcnt(5), NO block barriers in the main loop.
// Lane (pg=lane&15, ng=lane>>4) owns the 4x4 output tile at (4*pg, 4*ng).
__global__ __launch_bounds__(256, 3)
void ssd_state_wpriv(const float* __restrict__ Xg,
                     const float* __restrict__ Ag,
                     const float* __restrict__ Bg,
                     float* __restrict__ dst,
                     int seglen)
{
    extern __shared__ float sm[];
    float* wseg  = sm;              // [seglen] weights
    float* stage = sm + seglen;     // 4 waves x 2 bufs x CHF floats (40 KB)

    const int tid = threadIdx.x;
    const int bid = blockIdx.x;
    const int bh  = bid & (NBH - 1);
    const int g   = bid >> 9;       // log2(NBH) = 9
    const int b   = bh >> 3;
    const int h   = bh & 7;
    const int t0  = g * seglen;

    // ---------------- phase 1: wseg[t] = exp(sum_{s>t} A[b,s,h]) ----------------
    const float* Ab = Ag + (size_t)b * SEQ * NH + h;
    float a[8];
#pragma unroll
    for (int k = 0; k < 8; ++k)
        a[k] = Ab[(size_t)(tid * 8 + k) * NH];
    float tot = 0.f;
#pragma unroll
    for (int k = 0; k < 8; ++k) tot += a[k];
    stage[tid] = tot;               // scan scratch aliases staging area
    __syncthreads();
    for (int off = 1; off < 256; off <<= 1) {
        float v = stage[tid];
        float u = (tid + off < 256) ? stage[tid + off] : 0.f;
        __syncthreads();
        stage[tid] = v + u;
        __syncthreads();
    }
    float run = (tid < 255) ? stage[tid + 1] : 0.f;   // sum over s >= (tid+1)*8
#pragma unroll
    for (int k = 7; k >= 0; --k) {
        int t = tid * 8 + k;
        if (t >= t0 && t < t0 + seglen)
            wseg[t - t0] = expf(run);
        run += a[k];
    }
    __syncthreads();   // wseg ready; scan scratch dead -> staging may begin

    // ---------------- phase 2: wave-private double-buffered pipeline ------------
    const int wave = tid >> 6;
    const int lane = tid & 63;
    const int pg = lane & 15;
    const int ng = lane >> 4;

    const int WT  = seglen >> 2;       // timesteps per wave
    const int NCH = WT >> 4;           // 16-t chunks per wave
    const int wt0 = wave * WT;         // wave's t-offset within segment

    const float* Xrow = Xg + (((size_t)b * SEQ + t0) * NH + h) * DH;
    const float* Brow = Bg + (((size_t)b * SEQ + t0) * NH + h) * DS;
    float* bufA = stage + (wave * 2 + 0) * CHF;
    float* bufB = stage + (wave * 2 + 1) * CHF;

    float acc[4][4];
#pragma unroll
    for (int i = 0; i < 4; ++i)
#pragma unroll
        for (int j = 0; j < 4; ++j) acc[i][j] = 0.f;

    // prologue: chunks 0,1 in flight (10 vmem ops outstanding)
    stage16(Xrow, Brow, bufA, wt0 + 0 * CT, lane);
    stage16(Xrow, Brow, bufB, wt0 + (NCH > 1 ? 1 : 0) * CT, lane);

#pragma unroll 1
    for (int c = 0; c < NCH; ++c) {
        float* buf = (c & 1) ? bufB : bufA;
        // own chunk c landed (chunk c+1 stays in flight) — per-wave wait
        asm volatile("s_waitcnt vmcnt(5)" ::: "memory");
        __builtin_amdgcn_sched_barrier(0);

        const float* Xb = buf;
        const float* Bb = buf + XCH;
        const float* wp = wseg + wt0 + c * CT;
#pragma unroll
        for (int i = 0; i < CT; ++i) {
            f4 xv = *(const f4*)(Xb + i * DH + pg * 4);
            f4 bv = *(const f4*)(Bb + i * DS + ng * 4);
            float wt = wp[i];
            float s0 = xv.x * wt, s1 = xv.y * wt, s2 = xv.z * wt, s3 = xv.w * wt;
            acc[0][0] = fmaf(s0, bv.x, acc[0][0]);
            acc[0][1] = fmaf(s0, bv.y, acc[0][1]);
            acc[0][2] = fmaf(s0, bv.z, acc[0][2]);
            acc[0][3] = fmaf(s0, bv.w, acc[0][3]);
            acc[1][0] = fmaf(s1, bv.x, acc[1][0]);
            acc[1][1] = fmaf(s1, bv.y, acc[1][1]);
            acc[1][2] = fmaf(s1, bv.z, acc[1][2]);
            acc[1][3] = fmaf(s1, bv.w, acc[1][3]);
            acc[2][0] = fmaf(s2, bv.x, acc[2][0]);
            acc[2][1] = fmaf(s2, bv.y, acc[2][1]);
            acc[2][2] = fmaf(s2, bv.z, acc[2][2]);
            acc[2][3] = fmaf(s2, bv.w, acc[2][3]);
            acc[3][0] = fmaf(s3, bv.x, acc[3][0]);
            acc[3][1] = fmaf(s3, bv.y, acc[3][1]);
            acc[3][2] = fmaf(s3, bv.z, acc[3][2]);
            acc[3][3] = fmaf(s3, bv.w, acc[3][3]);
        }

        // drain this wave's ds_reads of buf, then re-stage chunk c+2 into it
        // (HW does not order incoming gload_lds writes vs pending ds_reads)
        asm volatile("s_waitcnt lgkmcnt(0)" ::: "memory");
        __builtin_amdgcn_sched_barrier(0);
        {
            int nxt = (c + 2 < NCH) ? c + 2 : NCH - 1;   // clamp: uniform 5 ops
            stage16(Xrow, Brow, buf, wt0 + nxt * CT, lane);
        }
    }

    // drain outstanding clamped stages before re-using staging LDS for reduce
    asm volatile("s_waitcnt vmcnt(0)" ::: "memory");
    __syncthreads();

    // ---------------- phase 3: cross-wave reduce + store (RS=18, conflict-free) -
    float* red = stage;
    {
        float* rw = red + wave * WSTR;
#pragma unroll
        for (int i = 0; i < 4; ++i) {
            float* row = rw + (pg * 4 + i) * RS + ng * 4;
            row[0] = acc[i][0];
            row[1] = acc[i][1];
            row[2] = acc[i][2];
            row[3] = acc[i][3];
        }
    }
    __syncthreads();
    {
        int e = tid * 4;
        int r = e >> 4, cc = e & 15;
        const float* rp = red + r * RS + cc;
        f4 sv;
        sv.x = rp[0] + rp[WSTR] + rp[2 * WSTR] + rp[3 * WSTR];
        sv.y = rp[1] + rp[1 + WSTR] + rp[1 + 2 * WSTR] + rp[1 + 3 * WSTR];
        sv.z = rp[2] + rp[2 + WSTR] + rp[2 + 2 * WSTR] + rp[2 + 3 * WSTR];
        sv.w = rp[3] + rp[3 + WSTR] + rp[3 + 2 * WSTR] + rp[3 + 3 * WSTR];
        *(f4*)(dst + (size_t)bid * OUTBH + e) = sv;
    }
}

// Sum the NSEG=4 segment partials into the final output.
__global__ __launch_bounds__(256)
void seg_reduce4(const float* __restrict__ part, float* __restrict__ out)
{
    int i = blockIdx.x * 256 + threadIdx.x;
    size_t o = (size_t)i * 4;
    float4 s = make_float4(0.f, 0.f, 0.f, 0.f);
#pragma unroll
    for (int g2 = 0; g2 < 4; ++g2) {
        float4 v = *(const float4*)(part + (size_t)g2 * NBH * OUTBH + o);
        s.x += v.x; s.y += v.y; s.z += v.z; s.w += v.w;
    }
    *(float4*)(out + o) = s;
}

extern "C" void kernel_launch(void* const* d_in, const int* in_sizes, int n_in,
                              void* d_out, int out_size, void* d_ws, size_t ws_size,
                              hipStream_t stream)
{
    const float* X  = (const float*)d_in[0];
    const float* A  = (const float*)d_in[1];
    const float* Bm = (const float*)d_in[2];
    // d_in[3] (C) is unused by the reference output.
    float* out = (float*)d_out;

    const size_t need = (size_t)4 * NBH * OUTBH * sizeof(float);  // 8 MB
    const int nseg   = (d_ws && ws_size >= need) ? 4 : 1;
    const int seglen = SEQ / nseg;
    float* dst = (nseg == 4) ? (float*)d_ws : out;
    const size_t lds = (size_t)(seglen + 8 * CHF) * sizeof(float);

    ssd_state_wpriv<<<dim3(nseg * NBH), dim3(256), lds, stream>>>(X, A, Bm, dst, seglen);
    if (nseg == 4)
        seg_reduce4<<<dim3((NBH * OUTBH) / 1024), dim3(256), 0, stream>>>((const float*)d_ws, out);
}